// Round 7
// baseline (111.558 us; speedup 1.0000x reference)
//
#include <hip/hip_runtime.h>

#define N_NODES 50000
#define N_EDGES 600000
#define DIM 128
#define BM 64
#define SCAN_BLOCKS ((N_NODES + 255) / 256)   // 196

typedef __attribute__((ext_vector_type(8))) short short8;
typedef __attribute__((ext_vector_type(4))) float f32x4;

__device__ __forceinline__ unsigned bf16rne(float f) {
  unsigned x = __float_as_uint(f);
  x += 0x7fffu + ((x >> 16) & 1u);
  return x >> 16;
}

__device__ __forceinline__ void fma8(float* a, uint4 v, float w) {
  a[0] += __uint_as_float(v.x << 16) * w;
  a[1] += __uint_as_float(v.x & 0xffff0000u) * w;
  a[2] += __uint_as_float(v.y << 16) * w;
  a[3] += __uint_as_float(v.y & 0xffff0000u) * w;
  a[4] += __uint_as_float(v.z << 16) * w;
  a[5] += __uint_as_float(v.z & 0xffff0000u) * w;
  a[6] += __uint_as_float(v.w << 16) * w;
  a[7] += __uint_as_float(v.w & 0xffff0000u) * w;
}

// ---------------------------------------------------------------------------
// K1: nf -> bf16, W -> bf16, deg = 0, gtotal = 0   (one dispatch)
// ---------------------------------------------------------------------------
__global__ __launch_bounds__(256) void cvt_all(
    const float4* __restrict__ nf4, uint2* __restrict__ nf16d,
    const float4* __restrict__ w4, uint2* __restrict__ w16d,
    int* __restrict__ deg, int* __restrict__ gtotal) {
  int i = blockIdx.x * 256 + threadIdx.x;
  if (i == 0) *gtotal = 0;
  if (i < N_NODES) deg[i] = 0;
  if (i < DIM * 2 * DIM / 4) {
    float4 v = w4[i];
    uint2 o;
    o.x = bf16rne(v.x) | (bf16rne(v.y) << 16);
    o.y = bf16rne(v.z) | (bf16rne(v.w) << 16);
    w16d[i] = o;
  }
  if (i < N_NODES * DIM / 4) {
    float4 v = nf4[i];
    uint2 o;
    o.x = bf16rne(v.x) | (bf16rne(v.y) << 16);
    o.y = bf16rne(v.z) | (bf16rne(v.w) << 16);
    nf16d[i] = o;
  }
}

// ---------------------------------------------------------------------------
// K2: rank[e] = deg[dst[e]]++   (atomic return -> coalesced store)
// ---------------------------------------------------------------------------
__global__ __launch_bounds__(256) void hist_deg(
    const int* __restrict__ dst, int* __restrict__ deg, int* __restrict__ rank) {
  int e = blockIdx.x * 256 + threadIdx.x;
  if (e < N_EDGES) rank[e] = atomicAdd(&deg[dst[e]], 1);
}

// ---------------------------------------------------------------------------
// K3: fused scan. Block-local exclusive scan; block base obtained in
// ARRIVAL order via atomicAdd(gtotal, block_total) — CSR buckets only
// need disjoint ranges, not node-order-monotone bases.
// ---------------------------------------------------------------------------
__global__ __launch_bounds__(256) void scan_fused(
    const int* __restrict__ deg, int* __restrict__ cursor,
    int* __restrict__ gtotal) {
  __shared__ int s[256];
  __shared__ int base;
  int t = threadIdx.x;
  int i = blockIdx.x * 256 + t;
  int v = (i < N_NODES) ? deg[i] : 0;
  s[t] = v;
  __syncthreads();
#pragma unroll
  for (int d = 1; d < 256; d <<= 1) {
    int add = (t >= d) ? s[t - d] : 0;
    __syncthreads();
    s[t] += add;
    __syncthreads();
  }
  int incl = s[t];
  if (t == 255) base = atomicAdd(gtotal, incl);
  __syncthreads();
  if (i < N_NODES) cursor[i] = base + incl - v;
}

// ---------------------------------------------------------------------------
// K4: srcw[cursor[dst[e]] + rank[e]] = src | (u16(w*65535) << 16)  (no atomics)
// ---------------------------------------------------------------------------
__global__ __launch_bounds__(256) void scatter_edges(
    const int* __restrict__ src, const int* __restrict__ dst,
    const float* __restrict__ ew, const int* __restrict__ cursor,
    const int* __restrict__ rank, unsigned* __restrict__ srcw) {
  int e = blockIdx.x * 256 + threadIdx.x;
  if (e >= N_EDGES) return;
  int pos = cursor[dst[e]] + rank[e];
  unsigned wq = (unsigned)rintf(ew[e] * 65535.0f);
  srcw[pos] = (unsigned)src[e] | (wq << 16);
}

// ---------------------------------------------------------------------------
// K5: gather. wave = 8 groups x 8 lanes; group g takes edges j = g, g+8, ...
// UNROLL 2: each iteration processes j and j+8 -> 4 independent uint4 row
// loads in flight; avg degree 12 completes in ONE latency window.
// Reduce shfl_xor 8/16/32 over 16 accs; group 0 writes the 256B row.
// ---------------------------------------------------------------------------
__global__ __launch_bounds__(256) void gather_nodes_bf16(
    const uint4* __restrict__ nfq,   // [N][16] granules of 8 bf16
    const int* __restrict__ cursor, const int* __restrict__ deg,
    const unsigned* __restrict__ srcw, uint4* __restrict__ aggq) {
  int node = blockIdx.x * 4 + (threadIdx.x >> 6);
  int lane = threadIdx.x & 63;
  int g = lane >> 3;          // edge group 0..7
  int c = lane & 7;           // 32B feature chunk 0..7
  int dg = deg[node];
  int off = cursor[node];

  float a[16];
#pragma unroll
  for (int k = 0; k < 16; ++k) a[k] = 0.f;

  for (int j = g; j < dg; j += 16) {
    unsigned q0 = srcw[off + j];
    bool h2 = (j + 8) < dg;
    unsigned q1 = h2 ? srcw[off + j + 8] : q0;
    float w0 = (float)(q0 >> 16) * (1.0f / 65535.0f);
    float w1 = h2 ? (float)(q1 >> 16) * (1.0f / 65535.0f) : 0.0f;
    const uint4* r0 = nfq + (size_t)(q0 & 0xffffu) * 16 + c * 2;
    const uint4* r1 = nfq + (size_t)(q1 & 0xffffu) * 16 + c * 2;
    uint4 v0 = r0[0];
    uint4 v1 = r0[1];
    uint4 v2 = r1[0];
    uint4 v3 = r1[1];
    fma8(a, v0, w0);
    fma8(a + 8, v1, w0);
    fma8(a, v2, w1);
    fma8(a + 8, v3, w1);
  }
#pragma unroll
  for (int k = 0; k < 16; ++k) {
    a[k] += __shfl_xor(a[k], 8);
    a[k] += __shfl_xor(a[k], 16);
    a[k] += __shfl_xor(a[k], 32);
  }
  if (g == 0) {
    float inv = 1.0f / (float)max(dg, 1);
    uint4 o0, o1;
    o0.x = bf16rne(a[0] * inv)  | (bf16rne(a[1] * inv) << 16);
    o0.y = bf16rne(a[2] * inv)  | (bf16rne(a[3] * inv) << 16);
    o0.z = bf16rne(a[4] * inv)  | (bf16rne(a[5] * inv) << 16);
    o0.w = bf16rne(a[6] * inv)  | (bf16rne(a[7] * inv) << 16);
    o1.x = bf16rne(a[8] * inv)  | (bf16rne(a[9] * inv) << 16);
    o1.y = bf16rne(a[10] * inv) | (bf16rne(a[11] * inv) << 16);
    o1.z = bf16rne(a[12] * inv) | (bf16rne(a[13] * inv) << 16);
    o1.w = bf16rne(a[14] * inv) | (bf16rne(a[15] * inv) << 16);
    aggq[(size_t)node * 16 + c * 2]     = o0;
    aggq[(size_t)node * 16 + c * 2 + 1] = o1;
  }
}

// ---------------------------------------------------------------------------
// K6: out[n,o] = sum_k [h16|nf16][n,k] * W16[o,k] + b[o]   (MFMA, K=256)
// BM=64: 782 blocks (2x TLP vs BM=128). Wave tile 64x32 (4x2 frags);
// all 4 waves read the SAME A rows (fetched once), W stays L2-hot.
// ---------------------------------------------------------------------------
__global__ __launch_bounds__(256) void gemm_mfma(
    const char* __restrict__ h16,   // [N][128] bf16
    const char* __restrict__ nf16,  // [N][128] bf16
    const char* __restrict__ w16,   // [128][256] bf16
    const float* __restrict__ bias,
    float* __restrict__ out) {
  const int tid = threadIdx.x;
  const int node0 = blockIdx.x * BM;
  const int lane = tid & 63;
  const int wv = tid >> 6;              // 0..3 -> output cols wv*32..+32
  const int l16 = lane & 15, lg = lane >> 4;

  f32x4 acc[4][2] = {};
#pragma unroll
  for (int ks = 0; ks < 8; ++ks) {
    const char* abase = (ks < 4) ? h16 : nf16;
    const int gbyte = (ks & 3) * 64 + lg * 16;
    short8 a[4], b[2];
#pragma unroll
    for (int m = 0; m < 4; ++m) {
      int node = node0 + m * 16 + l16;
      if (node > N_NODES - 1) node = N_NODES - 1;
      a[m] = *reinterpret_cast<const short8*>(abase + (size_t)node * 256 + gbyte);
    }
#pragma unroll
    for (int n = 0; n < 2; ++n) {
      int r = wv * 32 + n * 16 + l16;
      b[n] = *reinterpret_cast<const short8*>(w16 + (size_t)r * 512 + ks * 64 + lg * 16);
    }
#pragma unroll
    for (int m = 0; m < 4; ++m)
#pragma unroll
      for (int n = 0; n < 2; ++n)
        acc[m][n] = __builtin_amdgcn_mfma_f32_16x16x32_bf16(a[m], b[n], acc[m][n], 0, 0, 0);
  }

#pragma unroll
  for (int m = 0; m < 4; ++m) {
    int row_base = node0 + m * 16 + lg * 4;
#pragma unroll
    for (int n = 0; n < 2; ++n) {
      int o = wv * 32 + n * 16 + l16;
      float bv = bias[o];
#pragma unroll
      for (int j = 0; j < 4; ++j) {
        int node = row_base + j;
        if (node < N_NODES) out[(size_t)node * DIM + o] = acc[m][n][j] + bv;
      }
    }
  }
}

extern "C" void kernel_launch(void* const* d_in, const int* in_sizes, int n_in,
                              void* d_out, int out_size, void* d_ws, size_t ws_size,
                              hipStream_t stream) {
  const float* nf  = (const float*)d_in[0];  // [N, 128]
  const float* ew  = (const float*)d_in[1];  // [E, 1]
  const float* W   = (const float*)d_in[2];  // [128, 256]
  const float* b   = (const float*)d_in[3];  // [128]
  const int*   src = (const int*)d_in[4];    // [E]
  const int*   dst = (const int*)d_in[5];    // [E]
  float* out = (float*)d_out;                // [N, 128]

  // workspace layout (~30.9 MB of the ~256 MiB ws)
  char* ws = (char*)d_ws;
  char* agg16 = ws;                                   // 12,800,000
  char* nf16  = agg16 + (size_t)N_NODES * DIM * 2;    // 12,800,000
  char* w16   = nf16 + (size_t)N_NODES * DIM * 2;     // 65,536
  int*  deg    = (int*)(w16 + DIM * 2 * DIM * 2);     // 200,000
  int*  cursor = deg + N_NODES;                       // 200,000
  int*  gtotal = cursor + N_NODES;                    // 4 (+pad to 1024)
  int*  rank   = gtotal + 256;                        // 2,400,000
  unsigned* srcw = (unsigned*)(rank + N_EDGES);       // 2,400,000

  cvt_all<<<(N_NODES * DIM / 4 + 255) / 256, 256, 0, stream>>>(
      (const float4*)nf, (uint2*)nf16, (const float4*)W, (uint2*)w16, deg, gtotal);
  hist_deg<<<(N_EDGES + 255) / 256, 256, 0, stream>>>(dst, deg, rank);
  scan_fused<<<SCAN_BLOCKS, 256, 0, stream>>>(deg, cursor, gtotal);
  scatter_edges<<<(N_EDGES + 255) / 256, 256, 0, stream>>>(
      src, dst, ew, cursor, rank, srcw);
  gather_nodes_bf16<<<N_NODES / 4, 256, 0, stream>>>(
      (const uint4*)nf16, cursor, deg, srcw, (uint4*)agg16);
  gemm_mfma<<<(N_NODES + BM - 1) / BM, 256, 0, stream>>>(
      agg16, nf16, w16, b, out);
}